// Round 7
// baseline (304.051 us; speedup 1.0000x reference)
//
#include <hip/hip_runtime.h>

#define NN 50000
#define NE 800000
#define HID 256
#define HALF 128
#define NBLK ((NN + 255) / 256)   // 196
#define MT ((NN + 63) / 64)       // 782 GEMM m-tiles

typedef __attribute__((ext_vector_type(8))) short short8;   // bf16x8 frag (4 VGPR)
typedef __attribute__((ext_vector_type(4))) float floatx4;  // fp32 acc frag

// fp32 -> bf16 round-nearest-even (finite inputs)
__device__ inline unsigned short f2b(float f) {
    unsigned int u = __float_as_uint(f);
    unsigned int r = (u + 0x7FFFu + ((u >> 16) & 1u)) >> 16;
    return (unsigned short)r;
}
// packed bf16 halves -> fp32 (exact)
__device__ inline float blo(unsigned u) { return __uint_as_float(u << 16); }
__device__ inline float bhi(unsigned u) { return __uint_as_float(u & 0xFFFF0000u); }

// ---------- setup (fused): Wt[n][k]=bf16(Wc[k][n]); degq[n]=0 --------------
__global__ __launch_bounds__(256) void k_setup(const float* __restrict__ Wc,
                                               unsigned short* __restrict__ Wt,
                                               unsigned long long* __restrict__ degq) {
    int t = blockIdx.x * 256 + threadIdx.x;   // 65536
    int n = t >> 8, k = t & 255;
    Wt[n * 256 + k] = f2b(Wc[k * 256 + n]);
    if (t < NN) degq[t] = 0ull;
}

// ---- edge MLP: w[e]=sigmoid(silu(ea@W1+b1)@W2+b2); degq[col] += {1,q(w)}
// ea staged via LDS (float4 coalesced); weights in LDS; NE % 256 == 0
__global__ __launch_bounds__(256) void k_edge_mlp(
    const float* __restrict__ ea, const int* __restrict__ eidx,
    const float* __restrict__ W1, const float* __restrict__ b1,
    const float* __restrict__ W2, const float* __restrict__ b2,
    float* __restrict__ w, unsigned long long* __restrict__ degq) {
    __shared__ float4 wp[HALF];   // {W1[0][j], W1[1][j], W1[2][j], b1[j]}
    __shared__ float w2s[HALF];
    __shared__ float eas[768];    // 256 edges x 3 attrs
    int tid = threadIdx.x;
    int e0 = blockIdx.x * 256;
    if (tid < HALF) {
        wp[tid] = make_float4(W1[tid], W1[HALF + tid], W1[2 * HALF + tid], b1[tid]);
        w2s[tid] = W2[tid];
    }
    if (tid < 192)
        *(float4*)&eas[tid * 4] = *(const float4*)&ea[(size_t)e0 * 3 + tid * 4];
    __syncthreads();
    // stride-3 LDS read: 2-way bank aliasing across 64 lanes = free (m136)
    float a0 = eas[tid * 3], a1 = eas[tid * 3 + 1], a2 = eas[tid * 3 + 2];
    float acc = b2[0];
#pragma unroll 4
    for (int j = 0; j < HALF; ++j) {
        float4 wv = wp[j];                 // LDS broadcast (uniform addr, free)
        float t = fmaf(a0, wv.x, fmaf(a1, wv.y, fmaf(a2, wv.z, wv.w)));
        float s = t * __builtin_amdgcn_rcpf(1.0f + __expf(-t));   // silu
        acc = fmaf(s, w2s[j], acc);
    }
    int e = e0 + tid;
    float wv = __builtin_amdgcn_rcpf(1.0f + __expf(-acc));        // sigmoid
    w[e] = wv;
    int col = eidx[NE + e];
    // one u64 atomic: count in [63:48], fixed-point(2^-24) weight sum in [47:0]
    unsigned long long q = (1ull << 48) |
        (unsigned long long)__float2uint_rn(wv * 16777216.0f);
    atomicAdd(&degq[col], q);
}

// ------- scan phase 1 (fused degq unpack): dinv, per-block scan, bsum ------
__global__ __launch_bounds__(256) void k_scan_blk(
    const unsigned long long* __restrict__ degq, float* __restrict__ dinv,
    int* __restrict__ off, int* __restrict__ bsum) {
    __shared__ int smem[256];
    int tid = threadIdx.x;
    int idx = blockIdx.x * 256 + tid;
    int v = 0;
    if (idx < NN) {
        unsigned long long q = degq[idx];
        v = (int)(q >> 48);
        float d = fmaf((float)(q & 0xFFFFFFFFFFFFull), 5.9604644775390625e-8f, 1.0f);
        dinv[idx] = rsqrtf(d);   // d >= 1 always
    }
    smem[tid] = v;
    __syncthreads();
#pragma unroll
    for (int s = 1; s < 256; s <<= 1) {
        int t = (tid >= s) ? smem[tid - s] : 0;
        __syncthreads();
        smem[tid] += t;
        __syncthreads();
    }
    if (idx < NN) off[idx] = smem[tid] - v;
    if (tid == 255) bsum[blockIdx.x] = smem[255];
}

__global__ __launch_bounds__(256) void k_scan_top(const int* __restrict__ bsum,
                                                  int* __restrict__ bpre,
                                                  int* __restrict__ off) {
    __shared__ int smem[256];
    int tid = threadIdx.x;
    int v = (tid < NBLK) ? bsum[tid] : 0;
    smem[tid] = v;
    __syncthreads();
#pragma unroll
    for (int s = 1; s < 256; s <<= 1) {
        int t = (tid >= s) ? smem[tid - s] : 0;
        __syncthreads();
        smem[tid] += t;
        __syncthreads();
    }
    if (tid < NBLK) bpre[tid] = smem[tid] - v;
    if (tid == 255) off[NN] = smem[255];   // == NE
}

__global__ __launch_bounds__(256) void k_scan_add(const int* __restrict__ bpre,
                                                  int* __restrict__ off,
                                                  int* __restrict__ cursor) {
    int idx = blockIdx.x * 256 + threadIdx.x;
    if (idx < NN) {
        int o = off[idx] + bpre[blockIdx.x];
        off[idx] = o;
        cursor[idx] = o;
    }
}

// --- fill CSR: epk[p] = {row:16 | bf16(dinv[row]*w*dinv[col]):16} ----------
__global__ __launch_bounds__(256) void k_fill(
    const int* __restrict__ eidx, const float* __restrict__ w,
    const float* __restrict__ dinv, int* __restrict__ cursor,
    unsigned int* __restrict__ epk) {
    int e = blockIdx.x * 256 + threadIdx.x;
    if (e >= NE) return;
    int row = eidx[e];
    int col = eidx[NE + e];
    int p = atomicAdd(&cursor[col], 1);
    float nm = dinv[row] * w[e] * dinv[col];
    epk[p] = (unsigned)row | ((unsigned)f2b(nm) << 16);
}

// ------- xh = bf16(h @ Wc) via MFMA 16x16x32 -------------------------------
__global__ __launch_bounds__(256) void k_gemm_mfma(
    const float* __restrict__ A, const unsigned short* __restrict__ Wt,
    unsigned short* __restrict__ xh) {
    __shared__ __align__(16) unsigned short As[64][40];
    int tid = threadIdx.x;
    int wave = tid >> 6, lane = tid & 63;
    int mbase = blockIdx.x * 64;
    int nbase = wave * 64;
    int lrow = lane & 15;    // frag row/col within 16x16 tile
    int lg = lane >> 4;      // k-group (0..3): k = lg*8 + i
    floatx4 acc[4][4];
#pragma unroll
    for (int t = 0; t < 4; ++t)
#pragma unroll
        for (int u = 0; u < 4; ++u)
            acc[t][u] = (floatx4){0.f, 0.f, 0.f, 0.f};

    int srow = tid >> 2;     // 0..63 staging row
    int skg = tid & 3;       // k-group of 8
    int arow = mbase + srow;
    if (arow >= NN) arow = NN - 1;   // clamp: pollutes only OOB C rows

    for (int k0 = 0; k0 < 256; k0 += 32) {
        float4 f0 = *(const float4*)&A[arow * 256 + k0 + skg * 8];
        float4 f1 = *(const float4*)&A[arow * 256 + k0 + skg * 8 + 4];
        __syncthreads();   // previous iter's frag reads done
        uint4 pk;
        pk.x = (unsigned)f2b(f0.x) | ((unsigned)f2b(f0.y) << 16);
        pk.y = (unsigned)f2b(f0.z) | ((unsigned)f2b(f0.w) << 16);
        pk.z = (unsigned)f2b(f1.x) | ((unsigned)f2b(f1.y) << 16);
        pk.w = (unsigned)f2b(f1.z) | ((unsigned)f2b(f1.w) << 16);
        *(uint4*)&As[srow][skg * 8] = pk;
        __syncthreads();

        short8 af[4], bf[4];
#pragma unroll
        for (int t = 0; t < 4; ++t)
            af[t] = *(const short8*)&As[t * 16 + lrow][lg * 8];
#pragma unroll
        for (int u = 0; u < 4; ++u)
            bf[u] = *(const short8*)&Wt[(nbase + u * 16 + lrow) * 256 + k0 + lg * 8];
#pragma unroll
        for (int t = 0; t < 4; ++t)
#pragma unroll
            for (int u = 0; u < 4; ++u)
                acc[t][u] = __builtin_amdgcn_mfma_f32_16x16x32_bf16(
                    af[t], bf[u], acc[t][u], 0, 0, 0);
    }
    // C/D layout (m89-verified): col = lane&15, row = (lane>>4)*4 + reg
#pragma unroll
    for (int t = 0; t < 4; ++t) {
        int rowb = mbase + t * 16 + lg * 4;
#pragma unroll
        for (int r = 0; r < 4; ++r) {
            int row = rowb + r;
            if (row < NN) {
#pragma unroll
                for (int u = 0; u < 4; ++u)
                    xh[row * 256 + nbase + u * 16 + lrow] = f2b(acc[t][u][r]);
            }
        }
    }
}

// ------ aggregate: one wave per node, 8-unrolled bf16 gather, no atomics ---
__global__ __launch_bounds__(256) void k_aggregate(
    const unsigned short* __restrict__ xh, const int* __restrict__ off,
    const unsigned int* __restrict__ epk, const float* __restrict__ dinv,
    const float* __restrict__ bc, float* __restrict__ out) {
    int n = blockIdx.x * 4 + (threadIdx.x >> 6);
    int lane = threadIdx.x & 63;
    if (n >= NN) return;
    const uint2* xt = (const uint2*)xh;   // index: row*64 + lane (4 bf16 / lane)
    float di = dinv[n];
    float s = di * di;
    uint2 xv = xt[n * 64 + lane];
    float4 bv = *(const float4*)&bc[lane * 4];
    float ax = fmaf(blo(xv.x), s, bv.x);
    float ay = fmaf(bhi(xv.x), s, bv.y);
    float az = fmaf(blo(xv.y), s, bv.z);
    float aw = fmaf(bhi(xv.y), s, bv.w);
    int jb = off[n], je = off[n + 1];
    int j = jb;
    for (; j + 8 <= je; j += 8) {
        unsigned pe[8];
        uint2 g[8];
#pragma unroll
        for (int q = 0; q < 8; ++q) pe[q] = epk[j + q];
#pragma unroll
        for (int q = 0; q < 8; ++q)
            g[q] = xt[(pe[q] & 0xFFFFu) * 64 + lane];   // 8 gathers in flight
#pragma unroll
        for (int q = 0; q < 8; ++q) {
            float nm = bhi(pe[q]);                      // bf16 norm in high bits
            ax = fmaf(blo(g[q].x), nm, ax);
            ay = fmaf(bhi(g[q].x), nm, ay);
            az = fmaf(blo(g[q].y), nm, az);
            aw = fmaf(bhi(g[q].y), nm, aw);
        }
    }
    for (; j < je; ++j) {
        unsigned p = epk[j];
        float nm = bhi(p);
        uint2 v = xt[(p & 0xFFFFu) * 64 + lane];
        ax = fmaf(blo(v.x), nm, ax);
        ay = fmaf(bhi(v.x), nm, ay);
        az = fmaf(blo(v.y), nm, az);
        aw = fmaf(bhi(v.y), nm, aw);
    }
    *(float4*)&out[n * 256 + lane * 4] = make_float4(ax, ay, az, aw);
}

extern "C" void kernel_launch(void* const* d_in, const int* in_sizes, int n_in,
                              void* d_out, int out_size, void* d_ws, size_t ws_size,
                              hipStream_t stream) {
    const float* h   = (const float*)d_in[0];
    const int* eidx  = (const int*)d_in[1];   // [2, NE]: [0]=src(row), [1]=dst(col)
    const float* ea  = (const float*)d_in[2];
    const float* W1  = (const float*)d_in[3];
    const float* b1  = (const float*)d_in[4];
    const float* W2  = (const float*)d_in[5];
    const float* b2  = (const float*)d_in[6];
    const float* Wc  = (const float*)d_in[7];
    const float* bc  = (const float*)d_in[8];
    float* out = (float*)d_out;

    // workspace layout (~33 MB), all offsets 8B-aligned, re-inited each call
    char* p = (char*)d_ws;
    float* w                 = (float*)p;              p += (size_t)NE * 4;
    unsigned long long* degq = (unsigned long long*)p; p += (size_t)NN * 8;
    float* dinv              = (float*)p;              p += (size_t)NN * 4;
    unsigned short* xh       = (unsigned short*)p;     p += (size_t)NN * HID * 2;
    unsigned short* Wt       = (unsigned short*)p;     p += (size_t)HID * HID * 2;
    int* off                 = (int*)p;                p += (size_t)(NN + 2) * 4;
    int* cursor              = (int*)p;                p += (size_t)NN * 4;
    unsigned int* epk        = (unsigned int*)p;       p += (size_t)NE * 4;
    int* bsum                = (int*)p;                p += (size_t)NBLK * 4;
    int* bpre                = (int*)p;

    k_setup<<<(HID * HID) / 256, 256, 0, stream>>>(Wc, Wt, degq);
    k_edge_mlp<<<NE / 256, 256, 0, stream>>>(ea, eidx, W1, b1, W2, b2, w, degq);
    k_scan_blk<<<NBLK, 256, 0, stream>>>(degq, dinv, off, bsum);
    k_scan_top<<<1, 256, 0, stream>>>(bsum, bpre, off);
    k_scan_add<<<NBLK, 256, 0, stream>>>(bpre, off, cursor);
    k_fill<<<NE / 256, 256, 0, stream>>>(eidx, w, dinv, cursor, epk);
    k_gemm_mfma<<<MT, 256, 0, stream>>>(h, Wt, xh);
    k_aggregate<<<(NN + 3) / 4, 256, 0, stream>>>(xh, off, epk, dinv, bc, out);
}